// Round 2
// baseline (686.781 us; speedup 1.0000x reference)
//
#include <hip/hip_runtime.h>
#include <hip/hip_bf16.h>
#include <math.h>

// Problem constants: B=4, S=2048, E=2048, H=16, D=128. All dims hardcoded.
// Inputs/outputs are FP32 (verified via npz sizes); internal compute uses
// bf16 MFMA with f32 accumulation.

typedef __bf16 bf16_t;
typedef __bf16 bf16x4 __attribute__((ext_vector_type(4)));
typedef __bf16 bf16x8 __attribute__((ext_vector_type(8)));
typedef float f32x2 __attribute__((ext_vector_type(2)));
typedef float f32x4 __attribute__((ext_vector_type(4)));

typedef __attribute__((address_space(1))) const void gas_cvoid;
typedef __attribute__((address_space(3))) void las_void;

#define MFMA16(a, b, c) __builtin_amdgcn_mfma_f32_16x16x32_bf16((a), (b), (c), 0, 0, 0)

__device__ __forceinline__ void gload16(const void* g, void* l) {
  __builtin_amdgcn_global_load_lds((gas_cvoid*)g, (las_void*)l, 16, 0, 0);
}

// ---------------------------------------------------------------------------
// f32 -> bf16 elementwise (RNE), 4 elems/thread. n must be multiple of 1024.
// ---------------------------------------------------------------------------
__global__ __launch_bounds__(256) void cvt_bf16(const float* __restrict__ in,
                                                bf16_t* __restrict__ out) {
  const size_t i = ((size_t)blockIdx.x * 256 + threadIdx.x) * 4;
  f32x4 v = *(const f32x4*)&in[i];
  bf16x4 o;
#pragma unroll
  for (int j = 0; j < 4; ++j) o[j] = (bf16_t)v[j];
  *(bf16x4*)&out[i] = o;
}

// ---------------------------------------------------------------------------
// NT GEMM: C[M=8192][N=2048] = A[8192][2048] @ Bt[2048][2048]^T  (bf16 in, f32 acc)
// m97 structure: 128x128 tile, BK=32, 256 thr (4 waves, 2x2 of 64x64), global_load_lds.
// MODE 0: scatter bf16 C to [B,H,S,D];  MODE 1: plain row-major [M][N] of type CT.
// ---------------------------------------------------------------------------
template <int MODE, typename CT>
__global__ __launch_bounds__(256, 2) void gemm_bt(const bf16_t* __restrict__ A,
                                                  const bf16_t* __restrict__ Bt,
                                                  CT* __restrict__ C) {
  constexpr int K = 2048;
  __shared__ __attribute__((aligned(16))) bf16_t lds_a[128 * 32];
  __shared__ __attribute__((aligned(16))) bf16_t lds_b[128 * 32];
  const int tid = threadIdx.x;
  const int wave = tid >> 6, lane = tid & 63;
  // XCD-aware swizzle (grid 1024, 1024 % 8 == 0 -> simple form bijective)
  const int bid = blockIdx.x;
  const int swz = (bid & 7) * 128 + (bid >> 3);
  const int m0 = (swz >> 4) * 128, n0 = (swz & 15) * 128;

  const bf16_t* aS = A + (size_t)(m0 + (tid >> 2)) * K + (tid & 3) * 8;
  const bf16_t* bS = Bt + (size_t)(n0 + (tid >> 2)) * K + (tid & 3) * 8;
  char* la = (char*)lds_a + wave * 1024;
  char* lb = (char*)lds_b + wave * 1024;

  const int wm = wave >> 1, wn = wave & 1;
  const int l15 = lane & 15, l4 = lane >> 4;
  const int rA = (wm * 64 + l15) * 32 + l4 * 8;
  const int rB = (wn * 64 + l15) * 32 + l4 * 8;

  f32x4 acc[4][4] = {};

  for (int kt = 0; kt < K / 32; ++kt) {
    gload16(aS, la);
    gload16(aS + (size_t)64 * K, la + 4096);
    gload16(bS, lb);
    gload16(bS + (size_t)64 * K, lb + 4096);
    aS += 32;
    bS += 32;
    __syncthreads();
    bf16x8 af[4], bfr[4];
#pragma unroll
    for (int mi = 0; mi < 4; ++mi) af[mi] = *(const bf16x8*)&lds_a[rA + mi * 16 * 32];
#pragma unroll
    for (int ni = 0; ni < 4; ++ni) bfr[ni] = *(const bf16x8*)&lds_b[rB + ni * 16 * 32];
#pragma unroll
    for (int mi = 0; mi < 4; ++mi)
#pragma unroll
      for (int ni = 0; ni < 4; ++ni) acc[mi][ni] = MFMA16(af[mi], bfr[ni], acc[mi][ni]);
    __syncthreads();
  }

  const int rBase = m0 + wm * 64 + l4 * 4;
  const int cBase = n0 + wn * 64 + l15;
#pragma unroll
  for (int mi = 0; mi < 4; ++mi)
#pragma unroll
    for (int ni = 0; ni < 4; ++ni)
#pragma unroll
      for (int j = 0; j < 4; ++j) {
        const int r = rBase + mi * 16 + j;
        const int c = cBase + ni * 16;
        const CT v = (CT)acc[mi][ni][j];
        if (MODE == 0) {
          const int b = r >> 11, s = r & 2047, h = c >> 7, d = c & 127;
          C[(((size_t)(b * 16 + h)) * 2048 + s) * 128 + d] = v;
        } else {
          C[(size_t)r * 2048 + c] = v;
        }
      }
}

// ---------------------------------------------------------------------------
// Fused RoPE + RMSNorm, in place on a [B*H, S, D=128] bf16 tensor.
// One wave per row; lane handles d = 2*lane, 2*lane+1; rotate-half partner
// via shfl_xor(32). cos/sin read as f32 [S,128].
// ---------------------------------------------------------------------------
__global__ __launch_bounds__(256) void rope_rms(bf16_t* __restrict__ T,
                                                const float* __restrict__ Cs,
                                                const float* __restrict__ Sn) {
  const int wave = threadIdx.x >> 6, lane = threadIdx.x & 63;
#pragma unroll 1
  for (int rr = 0; rr < 8; ++rr) {
    const size_t row = (size_t)blockIdx.x * 32 + wave * 8 + rr;
    const int s = (int)(row & 2047);
    bf16_t* p = &T[row * 128 + 2 * lane];
    const float a0 = (float)p[0], a1 = (float)p[1];
    f32x2 cv = *(const f32x2*)&Cs[(size_t)s * 128 + 2 * lane];
    f32x2 sv = *(const f32x2*)&Sn[(size_t)s * 128 + 2 * lane];
    const float p0 = __shfl_xor(a0, 32);
    const float p1 = __shfl_xor(a1, 32);
    const float sg = (lane < 32) ? -1.f : 1.f;
    const float r0 = a0 * cv.x + sg * p0 * sv.x;
    const float r1 = a1 * cv.y + sg * p1 * sv.y;
    float ss = r0 * r0 + r1 * r1;
#pragma unroll
    for (int off = 1; off < 64; off <<= 1) ss += __shfl_xor(ss, off);
    const float inv = rsqrtf(ss * (1.0f / 128.0f) + 1e-6f);
    p[0] = (bf16_t)(r0 * inv);
    p[1] = (bf16_t)(r1 * inv);
  }
}

// ---------------------------------------------------------------------------
// Flash attention, non-causal. Q,K,V in [B*H][S=2048][D=128] bf16.
// 256 thr / 4 waves; 128 q-rows per block (32 per wave); KV tiles of 64.
// K: global_load_lds, XOR-swizzled source granule (conflict-free frag reads).
// V: transposed into LDS [128][72] via reg scatter (contiguous PV B-frags).
// P: wave-private LDS round-trip [32][72]. Online softmax in f32.
// Output Y bf16 in [B,S,H,D].
// ---------------------------------------------------------------------------
__global__ __launch_bounds__(256, 2) void attn_fwd(const bf16_t* __restrict__ Q,
                                                   const bf16_t* __restrict__ K,
                                                   const bf16_t* __restrict__ V,
                                                   bf16_t* __restrict__ Y) {
  __shared__ __attribute__((aligned(16))) bf16_t ldsK[64 * 128];    // swizzled row-major
  __shared__ __attribute__((aligned(16))) bf16_t ldsV[128 * 72];    // V^T, padded
  __shared__ __attribute__((aligned(16))) bf16_t ldsP[4 * 32 * 72]; // per-wave P
  const int tid = threadIdx.x, wave = tid >> 6, lane = tid & 63;
  const int bid = blockIdx.x;
  const int bh = bid >> 4, qb = bid & 15;
  const int b = bh >> 4, h = bh & 15;
  const bf16_t* Qh = Q + (size_t)bh * 2048 * 128;
  const bf16_t* Kh = K + (size_t)bh * 2048 * 128;
  const bf16_t* Vh = V + (size_t)bh * 2048 * 128;
  const int l15 = lane & 15, l4 = lane >> 4;

  // Q fragments in registers, reused for all KV tiles
  bf16x8 qf[2][4];
#pragma unroll
  for (int mi = 0; mi < 2; ++mi)
#pragma unroll
    for (int ks = 0; ks < 4; ++ks)
      qf[mi][ks] = *(const bf16x8*)&Qh[(size_t)(qb * 128 + wave * 32 + mi * 16 + l15) * 128 +
                                       ks * 32 + l4 * 8];

  f32x4 o[2][8] = {};
  float mrow[2][4], lrow[2][4];
#pragma unroll
  for (int mi = 0; mi < 2; ++mi)
#pragma unroll
    for (int j = 0; j < 4; ++j) {
      mrow[mi][j] = -1e30f;
      lrow[mi][j] = 0.f;
    }

  bf16_t* Pw = ldsP + wave * (32 * 72);
  const float scale = 0.088388347648318447f;  // 1/sqrt(128)

  for (int kt = 0; kt < 32; ++kt) {
    // ---- stage K tile [64][128] via global_load_lds, source-swizzled (granule ^= row&7)
#pragma unroll
    for (int i = 0; i < 4; ++i) {
      const int r = i * 16 + (tid >> 4);
      const int gs = (tid & 15) ^ (r & 7);
      gload16(Kh + (size_t)(kt * 64 + r) * 128 + gs * 8, (char*)ldsK + i * 4096 + wave * 1024);
    }
    // ---- stage V transposed: ldsV[d][kv], rows padded to 72
#pragma unroll
    for (int i = 0; i < 4; ++i) {
      const int kv = i * 16 + l15;
      const int dg = wave * 4 + l4;
      bf16x8 vv = *(const bf16x8*)&Vh[(size_t)(kt * 64 + kv) * 128 + dg * 8];
#pragma unroll
      for (int j = 0; j < 8; ++j) ldsV[(dg * 8 + j) * 72 + kv] = vv[j];
    }
    __syncthreads();

    // ---- S = Q @ K^T (per wave: 32 q x 64 kv)
    f32x4 sa[2][4] = {};
#pragma unroll
    for (int ks = 0; ks < 4; ++ks) {
      bf16x8 kf[4];
#pragma unroll
      for (int ni = 0; ni < 4; ++ni) {
        const int r = ni * 16 + l15;
        const int g = (ks * 4 + l4) ^ (r & 7);
        kf[ni] = *(const bf16x8*)((const char*)ldsK + r * 256 + g * 16);
      }
#pragma unroll
      for (int mi = 0; mi < 2; ++mi)
#pragma unroll
        for (int ni = 0; ni < 4; ++ni) sa[mi][ni] = MFMA16(qf[mi][ks], kf[ni], sa[mi][ni]);
    }

    // ---- online softmax (row q = mi*16 + l4*4 + j; reduce over l15 group via shfl)
#pragma unroll
    for (int mi = 0; mi < 2; ++mi)
#pragma unroll
      for (int j = 0; j < 4; ++j) {
        const float s0 = sa[mi][0][j] * scale, s1 = sa[mi][1][j] * scale;
        const float s2 = sa[mi][2][j] * scale, s3 = sa[mi][3][j] * scale;
        float mx = fmaxf(fmaxf(s0, s1), fmaxf(s2, s3));
#pragma unroll
        for (int off = 1; off < 16; off <<= 1) mx = fmaxf(mx, __shfl_xor(mx, off));
        const float mo = mrow[mi][j];
        const float mn = fmaxf(mo, mx);
        mrow[mi][j] = mn;
        const float corr = __expf(mo - mn);
        const float p0 = __expf(s0 - mn), p1 = __expf(s1 - mn);
        const float p2 = __expf(s2 - mn), p3 = __expf(s3 - mn);
        float ps = p0 + p1 + p2 + p3;
#pragma unroll
        for (int off = 1; off < 16; off <<= 1) ps += __shfl_xor(ps, off);
        lrow[mi][j] = lrow[mi][j] * corr + ps;
#pragma unroll
        for (int nd = 0; nd < 8; ++nd) o[mi][nd][j] *= corr;
        const int rw = (mi * 16 + l4 * 4 + j) * 72;
        Pw[rw + 0 * 16 + l15] = (bf16_t)p0;
        Pw[rw + 1 * 16 + l15] = (bf16_t)p1;
        Pw[rw + 2 * 16 + l15] = (bf16_t)p2;
        Pw[rw + 3 * 16 + l15] = (bf16_t)p3;
      }

    // ---- O += P @ V (wave-private P; same-wave DS ops are in order)
#pragma unroll
    for (int ks2 = 0; ks2 < 2; ++ks2) {
      bf16x8 pf[2];
#pragma unroll
      for (int mi = 0; mi < 2; ++mi)
        pf[mi] = *(const bf16x8*)&Pw[(mi * 16 + l15) * 72 + ks2 * 32 + l4 * 8];
#pragma unroll
      for (int nd = 0; nd < 8; ++nd) {
        bf16x8 vf = *(const bf16x8*)&ldsV[(nd * 16 + l15) * 72 + ks2 * 32 + l4 * 8];
#pragma unroll
        for (int mi = 0; mi < 2; ++mi) o[mi][nd] = MFMA16(pf[mi], vf, o[mi][nd]);
      }
    }
    __syncthreads();
  }

  // ---- epilogue: O /= l, write Y[b][s][h][d]
#pragma unroll
  for (int mi = 0; mi < 2; ++mi)
#pragma unroll
    for (int j = 0; j < 4; ++j) {
      const float rl = 1.0f / lrow[mi][j];
      const int srow = qb * 128 + wave * 32 + mi * 16 + l4 * 4 + j;
      const size_t base = (((size_t)b * 2048 + srow) * 16 + h) * 128 + l15;
#pragma unroll
      for (int nd = 0; nd < 8; ++nd) Y[base + nd * 16] = (bf16_t)(o[mi][nd][j] * rl);
    }
}

// ---------------------------------------------------------------------------
extern "C" void kernel_launch(void* const* d_in, const int* in_sizes, int n_in,
                              void* d_out, int out_size, void* d_ws, size_t ws_size,
                              hipStream_t stream) {
  const float* x = (const float*)d_in[0];
  const float* cs = (const float*)d_in[1];
  const float* sn = (const float*)d_in[2];
  const float* Wq = (const float*)d_in[3];
  const float* Wk = (const float*)d_in[4];
  const float* Wv = (const float*)d_in[5];
  const float* Wo = (const float*)d_in[6];

  bf16_t* ws = (bf16_t*)d_ws;
  const size_t TSZ = (size_t)4 * 2048 * 2048;  // 16.78M elems (= B*S*E = B*H*S*D)
  const size_t WSZ = (size_t)2048 * 2048;      // 4.19M elems
  bf16_t* xb = ws;            // x bf16; later reused as Y
  bf16_t* Wqb = ws + TSZ;
  bf16_t* Wkb = Wqb + WSZ;
  bf16_t* Wvb = Wkb + WSZ;
  bf16_t* Wob = Wvb + WSZ;
  bf16_t* Qb = ws + 2 * TSZ;
  bf16_t* Kb = Qb + TSZ;
  bf16_t* Vb = Kb + TSZ;
  bf16_t* Yb = xb;            // alias: x dead after QKV projections
  // total workspace: 5 * TSZ * 2B = 167.8 MB

  // f32 -> bf16 conversions
  cvt_bf16<<<16384, 256, 0, stream>>>(x, xb);
  cvt_bf16<<<4096, 256, 0, stream>>>(Wq, Wqb);
  cvt_bf16<<<4096, 256, 0, stream>>>(Wk, Wkb);
  cvt_bf16<<<4096, 256, 0, stream>>>(Wv, Wvb);
  cvt_bf16<<<4096, 256, 0, stream>>>(Wo, Wob);

  // QKV projections (write [B,H,S,D] bf16)
  gemm_bt<0, bf16_t><<<1024, 256, 0, stream>>>(xb, Wqb, Qb);
  gemm_bt<0, bf16_t><<<1024, 256, 0, stream>>>(xb, Wkb, Kb);
  gemm_bt<0, bf16_t><<<1024, 256, 0, stream>>>(xb, Wvb, Vb);
  // RoPE + RMSNorm in place on Q, K
  rope_rms<<<4096, 256, 0, stream>>>(Qb, cs, sn);
  rope_rms<<<4096, 256, 0, stream>>>(Kb, cs, sn);
  // Attention -> Y in [B,S,H*D] bf16 (aliases xb)
  attn_fwd<<<1024, 256, 0, stream>>>(Qb, Kb, Vb, Yb);
  // Output projection -> d_out [B,S,E] f32
  gemm_bt<1, float><<<1024, 256, 0, stream>>>(Yb, Wob, (float*)d_out);
}

// Round 3
// 571.490 us; speedup vs baseline: 1.2017x; 1.2017x over previous
//
#include <hip/hip_runtime.h>
#include <hip/hip_bf16.h>
#include <math.h>

// Problem constants: B=4, S=2048, E=2048, H=16, D=128. All dims hardcoded.
// Inputs/outputs FP32; internal compute bf16 MFMA with f32 accumulation.

typedef __bf16 bf16_t;
typedef __bf16 bf16x2 __attribute__((ext_vector_type(2)));
typedef __bf16 bf16x4 __attribute__((ext_vector_type(4)));
typedef __bf16 bf16x8 __attribute__((ext_vector_type(8)));
typedef float f32x2 __attribute__((ext_vector_type(2)));
typedef float f32x4 __attribute__((ext_vector_type(4)));
typedef float f32x16 __attribute__((ext_vector_type(16)));
typedef unsigned int u32;
typedef u32 u32x4 __attribute__((ext_vector_type(4)));

typedef __attribute__((address_space(1))) const void gas_cvoid;
typedef __attribute__((address_space(3))) void las_void;

#define MFMA16(a, b, c) __builtin_amdgcn_mfma_f32_16x16x32_bf16((a), (b), (c), 0, 0, 0)
#define MFMA32(a, b, c) __builtin_amdgcn_mfma_f32_32x32x16_bf16((a), (b), (c), 0, 0, 0)

__device__ __forceinline__ void gload16(const void* g, void* l) {
  __builtin_amdgcn_global_load_lds((gas_cvoid*)g, (las_void*)l, 16, 0, 0);
}

// ---------------------------------------------------------------------------
// f32 -> bf16 elementwise (RNE), 4 elems/thread.
// ---------------------------------------------------------------------------
__global__ __launch_bounds__(256) void cvt_bf16(const float* __restrict__ in,
                                                bf16_t* __restrict__ out) {
  const size_t i = ((size_t)blockIdx.x * 256 + threadIdx.x) * 4;
  f32x4 v = *(const f32x4*)&in[i];
  bf16x4 o;
#pragma unroll
  for (int j = 0; j < 4; ++j) o[j] = (bf16_t)v[j];
  *(bf16x4*)&out[i] = o;
}

// ---------------------------------------------------------------------------
// NT GEMM: C[M][N] = A[M][2048] @ B[N][2048]^T (both operands row-major [rows][K]).
// 128x128 tile, BK=32, 256 thr (4 waves 2x2), global_load_lds staging.
// MODE 0: M=8192,N=2048, scatter bf16 C to [B,H,S,D]
// MODE 1: M=8192,N=2048, plain row-major [M][N] of type CT
// MODE 2: M=2048(A=Wv),N=8192(B=x), write V^T layout [B*H][128][2048]
// NT_T = N/128 tiles.
// ---------------------------------------------------------------------------
template <int MODE, typename CT, int NT_T>
__global__ __launch_bounds__(256, 2) void gemm_bt(const bf16_t* __restrict__ A,
                                                  const bf16_t* __restrict__ Bt,
                                                  CT* __restrict__ C) {
  constexpr int K = 2048;
  __shared__ __attribute__((aligned(16))) bf16_t lds_a[128 * 32];
  __shared__ __attribute__((aligned(16))) bf16_t lds_b[128 * 32];
  const int tid = threadIdx.x;
  const int wave = tid >> 6, lane = tid & 63;
  const int bid = blockIdx.x;
  const int swz = (bid & 7) * 128 + (bid >> 3);  // grid 1024, bijective
  const int m0 = (swz / NT_T) * 128, n0 = (swz % NT_T) * 128;

  const bf16_t* aS = A + (size_t)(m0 + (tid >> 2)) * K + (tid & 3) * 8;
  const bf16_t* bS = Bt + (size_t)(n0 + (tid >> 2)) * K + (tid & 3) * 8;
  char* la = (char*)lds_a + wave * 1024;
  char* lb = (char*)lds_b + wave * 1024;

  const int wm = wave >> 1, wn = wave & 1;
  const int l15 = lane & 15, l4 = lane >> 4;
  const int rA = (wm * 64 + l15) * 32 + l4 * 8;
  const int rB = (wn * 64 + l15) * 32 + l4 * 8;

  f32x4 acc[4][4] = {};

  for (int kt = 0; kt < K / 32; ++kt) {
    gload16(aS, la);
    gload16(aS + (size_t)64 * K, la + 4096);
    gload16(bS, lb);
    gload16(bS + (size_t)64 * K, lb + 4096);
    aS += 32;
    bS += 32;
    __syncthreads();
    bf16x8 af[4], bfr[4];
#pragma unroll
    for (int mi = 0; mi < 4; ++mi) af[mi] = *(const bf16x8*)&lds_a[rA + mi * 16 * 32];
#pragma unroll
    for (int ni = 0; ni < 4; ++ni) bfr[ni] = *(const bf16x8*)&lds_b[rB + ni * 16 * 32];
#pragma unroll
    for (int mi = 0; mi < 4; ++mi)
#pragma unroll
      for (int ni = 0; ni < 4; ++ni) acc[mi][ni] = MFMA16(af[mi], bfr[ni], acc[mi][ni]);
    __syncthreads();
  }

  const int rBase = m0 + wm * 64 + l4 * 4;
  const int cBase = n0 + wn * 64 + l15;
#pragma unroll
  for (int mi = 0; mi < 4; ++mi)
#pragma unroll
    for (int ni = 0; ni < 4; ++ni)
#pragma unroll
      for (int j = 0; j < 4; ++j) {
        const int r = rBase + mi * 16 + j;
        const int c = cBase + ni * 16;
        const CT v = (CT)acc[mi][ni][j];
        if (MODE == 0) {
          const int b = r >> 11, s = r & 2047, hh = c >> 7, d = c & 127;
          C[(((size_t)(b * 16 + hh)) * 2048 + s) * 128 + d] = v;
        } else if (MODE == 1) {
          C[(size_t)r * 2048 + c] = v;
        } else {  // MODE 2: r = h*128+dd (weight row), c = b*2048+s
          const int hh = r >> 7, dd = r & 127, b = c >> 11, s = c & 2047;
          C[((size_t)(b * 16 + hh) * 128 + dd) * 2048 + s] = v;
        }
      }
}

// ---------------------------------------------------------------------------
// Fused RoPE + RMSNorm, in place on [B*H, S, D=128] bf16.
// One wave per row; lane d = 2*lane, 2*lane+1; partner via shfl_xor(32).
// ---------------------------------------------------------------------------
__global__ __launch_bounds__(256) void rope_rms(bf16_t* __restrict__ T,
                                                const float* __restrict__ Cs,
                                                const float* __restrict__ Sn) {
  const int wave = threadIdx.x >> 6, lane = threadIdx.x & 63;
#pragma unroll 1
  for (int rr = 0; rr < 8; ++rr) {
    const size_t row = (size_t)blockIdx.x * 32 + wave * 8 + rr;
    const int s = (int)(row & 2047);
    bf16_t* p = &T[row * 128 + 2 * lane];
    const float a0 = (float)p[0], a1 = (float)p[1];
    f32x2 cv = *(const f32x2*)&Cs[(size_t)s * 128 + 2 * lane];
    f32x2 sv = *(const f32x2*)&Sn[(size_t)s * 128 + 2 * lane];
    const float p0 = __shfl_xor(a0, 32);
    const float p1 = __shfl_xor(a1, 32);
    const float sg = (lane < 32) ? -1.f : 1.f;
    const float r0 = a0 * cv.x + sg * p0 * sv.x;
    const float r1 = a1 * cv.y + sg * p1 * sv.y;
    float ss = r0 * r0 + r1 * r1;
#pragma unroll
    for (int off = 1; off < 64; off <<= 1) ss += __shfl_xor(ss, off);
    const float inv = rsqrtf(ss * (1.0f / 128.0f) + 1e-6f);
    p[0] = (bf16_t)(r0 * inv);
    p[1] = (bf16_t)(r1 * inv);
  }
}

// ---------------------------------------------------------------------------
// Flash attention, non-causal, m214-style 8-wave 32x32 swapped-QK structure.
// Q,K in [B*H][2048][128]; Vt in [B*H][128][2048] (pre-transposed); Y bf16 [B,S,H,D].
// Block: 512 thr / 8 waves; each wave owns 32 q-rows (256/block); KV tile 64.
// QK^T swapped: sa = mfma(K, Q) -> S^T, col = q = lane&31 (P-row lane-local).
// PV as O^T = mfma(V^T, P) -> col = q again; corr/l lane-local throughout.
// K and V^T tiles staged via global_load_lds, XOR-swizzled source (granule ^= row&7),
// double-buffered, 1 barrier/kt. P redistributed via 16 packed shfl_xor(32)/kt.
// Defer-max online softmax (THR=8).
// ---------------------------------------------------------------------------
__global__ __launch_bounds__(512, 2) void attn_fwd(const bf16_t* __restrict__ Q,
                                                   const bf16_t* __restrict__ K,
                                                   const bf16_t* __restrict__ Vt,
                                                   bf16_t* __restrict__ Y) {
  __shared__ __attribute__((aligned(16))) bf16_t ldsK[2][64 * 128];
  __shared__ __attribute__((aligned(16))) bf16_t ldsV[2][128 * 64];
  const int tid = threadIdx.x, wave = tid >> 6, lane = tid & 63;
  const int l31 = lane & 31, hi = lane >> 5;
  // XCD-aware mapping: all 8 q-blocks of a head on one XCD (512 = 8 xcd * 8 heads * 8 qb)
  const int pid = blockIdx.x;
  const int bh = (pid & 7) * 8 + ((pid >> 3) & 7);
  const int qb = pid >> 6;
  const int b = bh >> 4, h = bh & 15;
  const bf16_t* Qh = Q + (size_t)bh * 2048 * 128;
  const bf16_t* Kh = K + (size_t)bh * 2048 * 128;
  const bf16_t* Vh = Vt + (size_t)bh * 128 * 2048;
  const int q0 = qb * 256 + wave * 32;

  // Q fragments (B-operand): lane holds Q[q0+l31][dk*16 + hi*8 + e]
  bf16x8 qf[8];
#pragma unroll
  for (int dk = 0; dk < 8; ++dk)
    qf[dk] = *(const bf16x8*)&Qh[(size_t)(q0 + l31) * 128 + dk * 16 + hi * 8];

  f32x16 ot[4] = {};          // O^T: rows d = db*32 + crow(r,hi), col q = l31
  float m_r = -1e30f, l_r = 0.f;
  const float scale = 0.08838834764831845f;  // 1/sqrt(128)

  auto stage = [&](int kt, int bu) {
#pragma unroll
    for (int i = 0; i < 2; ++i) {
      const int G = wave * 64 + lane + i * 512;         // granule index 0..1023
      char* dstK = (char*)&ldsK[bu][0] + (wave * 64 + i * 512) * 16;  // +lane*16 by HW
      char* dstV = (char*)&ldsV[bu][0] + (wave * 64 + i * 512) * 16;
      const int kvr = G >> 4, glk = G & 15;             // K tile: [64][16 granules]
      gload16(Kh + (size_t)(kt * 64 + kvr) * 128 + ((glk ^ (kvr & 7)) * 8), dstK);
      const int dr = G >> 3, glv = G & 7;               // V^T tile: [128][8 granules]
      gload16(Vh + (size_t)dr * 2048 + kt * 64 + ((glv ^ (dr & 7)) * 8), dstV);
    }
  };

  stage(0, 0);
  __syncthreads();

  for (int kt = 0; kt < 32; ++kt) {
    const int bu = kt & 1;
    if (kt < 31) stage(kt + 1, bu ^ 1);

    // ---- S^T = K @ Q^T : sa0 = kv 0..31, sa1 = kv 32..63 (col q = l31)
    f32x16 sa0 = {}, sa1 = {};
    const int r7 = l31 & 7;
#pragma unroll
    for (int dk = 0; dk < 8; ++dk) {
      const int g = ((dk << 1) | hi) ^ r7;
      bf16x8 kf0 = *(const bf16x8*)&ldsK[bu][l31 * 128 + g * 8];
      bf16x8 kf1 = *(const bf16x8*)&ldsK[bu][(32 + l31) * 128 + g * 8];
      sa0 = MFMA32(kf0, qf[dk], sa0);
      sa1 = MFMA32(kf1, qf[dk], sa1);
    }

    // ---- online softmax (row = my q; partner lane^32 holds other 32 kv)
    float mx = sa0[0];
#pragma unroll
    for (int j = 1; j < 16; ++j) mx = fmaxf(mx, sa0[j]);
#pragma unroll
    for (int j = 0; j < 16; ++j) mx = fmaxf(mx, sa1[j]);
    mx = fmaxf(mx, __shfl_xor(mx, 32));
    mx *= scale;
    if (__any(mx > m_r + 8.f)) {  // defer-max (T13)
      const float mn = fmaxf(m_r, mx);
      const float corr = __expf(m_r - mn);
      m_r = mn;
      l_r *= corr;
#pragma unroll
      for (int db = 0; db < 4; ++db)
#pragma unroll
        for (int j = 0; j < 16; ++j) ot[db][j] *= corr;
    }
    // p = exp(s*scale - m), pack to bf16 pairs: w[t][i] = (P[kv0], P[kv0+1])
    u32 w[2][8];
    float ssum = 0.f;
#pragma unroll
    for (int i = 0; i < 8; ++i) {
      const float p0 = __expf(sa0[2 * i] * scale - m_r);
      const float p1 = __expf(sa0[2 * i + 1] * scale - m_r);
      const float p2 = __expf(sa1[2 * i] * scale - m_r);
      const float p3 = __expf(sa1[2 * i + 1] * scale - m_r);
      ssum += (p0 + p1) + (p2 + p3);
      bf16x2 t0, t1;
      t0[0] = (bf16_t)p0; t0[1] = (bf16_t)p1;
      t1[0] = (bf16_t)p2; t1[1] = (bf16_t)p3;
      w[0][i] = __builtin_bit_cast(u32, t0);
      w[1][i] = __builtin_bit_cast(u32, t1);
    }
    ssum += __shfl_xor(ssum, 32);
    l_r += ssum;

    // ---- O^T += V^T @ P : per ks (16 kv), assemble P B-frag via shfl_xor(32)
#pragma unroll
    for (int ks = 0; ks < 4; ++ks) {
      const int t = ks >> 1, k4 = (ks & 1) * 4;
      const u32 x0 = (u32)__shfl_xor((int)w[t][k4 + 0], 32);
      const u32 x1 = (u32)__shfl_xor((int)w[t][k4 + 1], 32);
      const u32 x2 = (u32)__shfl_xor((int)w[t][k4 + 2], 32);
      const u32 x3 = (u32)__shfl_xor((int)w[t][k4 + 3], 32);
      u32x4 fw;
      fw.x = hi ? x2 : w[t][k4 + 0];  // elems 0-1 (owner hi=0)
      fw.y = hi ? x3 : w[t][k4 + 1];  // elems 2-3
      fw.z = hi ? w[t][k4 + 2] : x0;  // elems 4-5 (owner hi=1)
      fw.w = hi ? w[t][k4 + 3] : x1;  // elems 6-7
      const bf16x8 pf = __builtin_bit_cast(bf16x8, fw);
      const int gv = ((ks << 1) | hi) ^ r7;
#pragma unroll
      for (int db = 0; db < 4; ++db) {
        bf16x8 vf = *(const bf16x8*)&ldsV[bu][(db * 32 + l31) * 64 + gv * 8];
        ot[db] = MFMA32(vf, pf, ot[db]);
      }
    }
    __syncthreads();
  }

  // ---- epilogue: O^T/l -> Y[b][s=q0+l31][h][d], 8B packed stores
  const float rl = 1.f / l_r;
  const size_t yrow = ((size_t)(b * 2048 + q0 + l31) * 16 + h) * 128;
#pragma unroll
  for (int db = 0; db < 4; ++db)
#pragma unroll
    for (int g2 = 0; g2 < 4; ++g2) {
      bf16x4 ov;
#pragma unroll
      for (int j = 0; j < 4; ++j) ov[j] = (bf16_t)(ot[db][g2 * 4 + j] * rl);
      *(bf16x4*)&Y[yrow + db * 32 + g2 * 8 + hi * 4] = ov;
    }
}

// ---------------------------------------------------------------------------
extern "C" void kernel_launch(void* const* d_in, const int* in_sizes, int n_in,
                              void* d_out, int out_size, void* d_ws, size_t ws_size,
                              hipStream_t stream) {
  const float* x = (const float*)d_in[0];
  const float* cs = (const float*)d_in[1];
  const float* sn = (const float*)d_in[2];
  const float* Wq = (const float*)d_in[3];
  const float* Wk = (const float*)d_in[4];
  const float* Wv = (const float*)d_in[5];
  const float* Wo = (const float*)d_in[6];

  bf16_t* ws = (bf16_t*)d_ws;
  const size_t TSZ = (size_t)4 * 2048 * 2048;  // 16.78M elems
  const size_t WSZ = (size_t)2048 * 2048;      // 4.19M elems
  bf16_t* xb = ws;            // x bf16; later reused as Y
  bf16_t* Wqb = ws + TSZ;
  bf16_t* Wkb = Wqb + WSZ;
  bf16_t* Wvb = Wkb + WSZ;
  bf16_t* Wob = Wvb + WSZ;
  bf16_t* Qb = ws + 2 * TSZ;
  bf16_t* Kb = Qb + TSZ;
  bf16_t* Vtb = Kb + TSZ;
  bf16_t* Yb = xb;            // alias: x dead after QKV projections

  // f32 -> bf16
  cvt_bf16<<<16384, 256, 0, stream>>>(x, xb);
  cvt_bf16<<<4096, 256, 0, stream>>>(Wq, Wqb);
  cvt_bf16<<<4096, 256, 0, stream>>>(Wk, Wkb);
  cvt_bf16<<<4096, 256, 0, stream>>>(Wv, Wvb);
  cvt_bf16<<<4096, 256, 0, stream>>>(Wo, Wob);

  // Q,K projections -> [B,H,S,D]; V projection transposed -> V^T [B*H][128][2048]
  gemm_bt<0, bf16_t, 16><<<1024, 256, 0, stream>>>(xb, Wqb, Qb);
  gemm_bt<0, bf16_t, 16><<<1024, 256, 0, stream>>>(xb, Wkb, Kb);
  gemm_bt<2, bf16_t, 64><<<1024, 256, 0, stream>>>(Wvb, xb, Vtb);
  // RoPE + RMSNorm in place on Q, K
  rope_rms<<<4096, 256, 0, stream>>>(Qb, cs, sn);
  rope_rms<<<4096, 256, 0, stream>>>(Kb, cs, sn);
  // Attention -> Y [B,S,H*D] bf16
  attn_fwd<<<512, 512, 0, stream>>>(Qb, Kb, Vtb, Yb);
  // Output projection -> d_out [B,S,E] f32
  gemm_bt<1, float, 16><<<1024, 256, 0, stream>>>(Yb, Wob, (float*)d_out);
}

// Round 4
// 489.607 us; speedup vs baseline: 1.4027x; 1.1672x over previous
//
#include <hip/hip_runtime.h>
#include <hip/hip_bf16.h>
#include <math.h>

// B=4, S=2048, E=2048, H=16, D=128. Inputs/outputs FP32; internal bf16 MFMA, f32 acc.

typedef __bf16 bf16_t;
typedef __bf16 bf16x2 __attribute__((ext_vector_type(2)));
typedef __bf16 bf16x4 __attribute__((ext_vector_type(4)));
typedef __bf16 bf16x8 __attribute__((ext_vector_type(8)));
typedef float f32x2 __attribute__((ext_vector_type(2)));
typedef float f32x4 __attribute__((ext_vector_type(4)));
typedef float f32x16 __attribute__((ext_vector_type(16)));
typedef unsigned int u32;
typedef u32 u32x4 __attribute__((ext_vector_type(4)));

typedef __attribute__((address_space(1))) const void gas_cvoid;
typedef __attribute__((address_space(3))) void las_void;

#define MFMA16(a, b, c) __builtin_amdgcn_mfma_f32_16x16x32_bf16((a), (b), (c), 0, 0, 0)
#define MFMA32(a, b, c) __builtin_amdgcn_mfma_f32_32x32x16_bf16((a), (b), (c), 0, 0, 0)

__device__ __forceinline__ void gload16(const void* g, void* l) {
  __builtin_amdgcn_global_load_lds((gas_cvoid*)g, (las_void*)l, 16, 0, 0);
}
// lane[i] <-> lane[i+32] pairwise exchange of two regs (T12 primitive, m255):
// after: a = {a.lo, b.lo}, b = {a.hi, b.hi}
__device__ __forceinline__ void pl32(u32& a, u32& b) {
  asm volatile("v_permlane32_swap_b32 %0, %1" : "+v"(a), "+v"(b));
}

// ---------------------------------------------------------------------------
// f32 -> bf16 elementwise, 4 elems/thread.
// ---------------------------------------------------------------------------
__global__ __launch_bounds__(256) void cvt_bf16(const float* __restrict__ in,
                                                bf16_t* __restrict__ out) {
  const size_t i = ((size_t)blockIdx.x * 256 + threadIdx.x) * 4;
  f32x4 v = *(const f32x4*)&in[i];
  bf16x4 o;
#pragma unroll
  for (int j = 0; j < 4; ++j) o[j] = (bf16_t)v[j];
  *(bf16x4*)&out[i] = o;
}
// 4 weight matrices (4.19M elems each) in one launch: 4096 blocks per tensor.
__global__ __launch_bounds__(256) void cvt_w4(const float* __restrict__ w0,
                                              const float* __restrict__ w1,
                                              const float* __restrict__ w2,
                                              const float* __restrict__ w3,
                                              bf16_t* __restrict__ o0,
                                              bf16_t* __restrict__ o1,
                                              bf16_t* __restrict__ o2,
                                              bf16_t* __restrict__ o3) {
  const int which = blockIdx.x >> 12;
  const float* in = which == 0 ? w0 : which == 1 ? w1 : which == 2 ? w2 : w3;
  bf16_t* out = which == 0 ? o0 : which == 1 ? o1 : which == 2 ? o2 : o3;
  const size_t i = ((size_t)(blockIdx.x & 4095) * 256 + threadIdx.x) * 4;
  f32x4 v = *(const f32x4*)&in[i];
  bf16x4 o;
#pragma unroll
  for (int j = 0; j < 4; ++j) o[j] = (bf16_t)v[j];
  *(bf16x4*)&out[i] = o;
}

// ---------------------------------------------------------------------------
// 8-phase NT GEMM: C[M][N] = A[M][2048] @ Bt[N][2048]^T, 256x256 tile, BK=64.
// 512 thr / 8 waves (2M x 4N), per-wave 128x64 output, acc[8][4] f32x4.
// LDS 128 KiB: 2 dbuf x (A 32K + B 32K). T2 XOR-swizzle (pre-swizzled global
// source + XOR'd ds_read chunk). Per K-tile: 4 quadrant phases, each
// {ds_read frags; stage (ph0:A, ph1:B of tile t+1 -> other buf); s_barrier;
//  setprio(1); 16 MFMA; setprio(0); s_barrier}; phase-3 trailing barrier is
// __syncthreads (vmcnt drain -- loads have >=2 MFMA phases of cover).
// MODE 0: scatter bf16 [B,H,S,D]; MODE 1: row-major [M][2048] CT;
// MODE 2: V^T [B*H][128][2048]. NT_T = N/256.
// ---------------------------------------------------------------------------
template <int MODE, typename CT, int NT_T>
__global__ __launch_bounds__(512, 2) void gemm8(const bf16_t* __restrict__ A,
                                                const bf16_t* __restrict__ Bt,
                                                CT* __restrict__ C) {
  constexpr int K = 2048;
  __shared__ __attribute__((aligned(16))) char lds[131072];
  const int tid = threadIdx.x;
  const int wave = tid >> 6, lane = tid & 63;
  const int bid = blockIdx.x;
  const int swz = (bid & 7) * 32 + (bid >> 3);  // grid 256, bijective XCD swizzle
  const int m0 = (swz / NT_T) * 256, n0 = (swz % NT_T) * 256;

  // staging: thread covers (row = 64*cc + srow, chunk = tid&7), source chunk
  // pre-swizzled by ^ (row&7) so LDS[row][cd] holds global chunk cd^(row&7).
  const int srow = tid >> 3;
  const int scol = ((tid & 7) ^ (srow & 7)) * 8;
  const bf16_t* aBase = A + (size_t)(m0 + srow) * K + scol;
  const bf16_t* bBase = Bt + (size_t)(n0 + srow) * K + scol;

  const int wm = wave >> 2, wn = wave & 3;
  const int l15 = lane & 15, l4 = lane >> 4;
  const int axor = l15 & 7;

  f32x4 acc[8][4] = {};

  auto stageA = [&](int tt, int nbuf) {
#pragma unroll
    for (int h = 0; h < 2; ++h)
#pragma unroll
      for (int cc = 0; cc < 2; ++cc)
        gload16(aBase + (size_t)(h * 128 + cc * 64) * K + tt * 64,
                lds + nbuf * 65536 + h * 16384 + cc * 8192 + wave * 1024);
  };
  auto stageB = [&](int tt, int nbuf) {
#pragma unroll
    for (int h = 0; h < 2; ++h)
#pragma unroll
      for (int cc = 0; cc < 2; ++cc)
        gload16(bBase + (size_t)(h * 128 + cc * 64) * K + tt * 64,
                lds + nbuf * 65536 + 32768 + h * 16384 + cc * 8192 + wave * 1024);
  };

  stageA(0, 0);
  stageB(0, 0);
  __syncthreads();

  for (int t = 0; t < 32; ++t) {
    const int buf = t & 1, nbuf = buf ^ 1;
    const char* la = lds + buf * 65536 + wm * 16384;
    const char* lb = lds + buf * 65536 + 32768 + (wn >> 1) * 16384 + (wn & 1) * 8192;
    bf16x8 bF[4][2];
#pragma unroll
    for (int q = 0; q < 4; ++q) {
      bf16x8 aF[2][2];
#pragma unroll
      for (int dm = 0; dm < 2; ++dm)
#pragma unroll
        for (int kk = 0; kk < 2; ++kk)
          aF[dm][kk] = *(const bf16x8*)(la + ((q * 2 + dm) * 16 + l15) * 128 +
                                        ((kk * 4 + l4) ^ axor) * 16);
      if (q == 0) {
#pragma unroll
        for (int ni = 0; ni < 4; ++ni)
#pragma unroll
          for (int kk = 0; kk < 2; ++kk)
            bF[ni][kk] = *(const bf16x8*)(lb + (ni * 16 + l15) * 128 +
                                          ((kk * 4 + l4) ^ axor) * 16);
        if (t < 31) stageA(t + 1, nbuf);
      }
      if (q == 1 && t < 31) stageB(t + 1, nbuf);
      __builtin_amdgcn_s_barrier();
      __builtin_amdgcn_s_setprio(1);
#pragma unroll
      for (int kk = 0; kk < 2; ++kk)
#pragma unroll
        for (int dm = 0; dm < 2; ++dm)
#pragma unroll
          for (int ni = 0; ni < 4; ++ni)
            acc[q * 2 + dm][ni] = MFMA16(aF[dm][kk], bF[ni][kk], acc[q * 2 + dm][ni]);
      __builtin_amdgcn_s_setprio(0);
      if (q < 3)
        __builtin_amdgcn_s_barrier();
      else
        __syncthreads();  // drains vmcnt(0): tile t+1 landed; buf t free
    }
  }

  const int rBase = m0 + wm * 128 + l4 * 4;
  const int cBase = n0 + wn * 64 + l15;
#pragma unroll
  for (int mi = 0; mi < 8; ++mi)
#pragma unroll
    for (int ni = 0; ni < 4; ++ni)
#pragma unroll
      for (int j = 0; j < 4; ++j) {
        const int r = rBase + mi * 16 + j;
        const int c = cBase + ni * 16;
        const CT v = (CT)acc[mi][ni][j];
        if (MODE == 0) {
          const int b = r >> 11, s = r & 2047, hh = c >> 7, d = c & 127;
          C[(((size_t)(b * 16 + hh)) * 2048 + s) * 128 + d] = v;
        } else if (MODE == 1) {
          C[(size_t)r * 2048 + c] = v;
        } else {  // r = h*128+dd (Wv row), c = b*2048+s
          const int hh = r >> 7, dd = r & 127, b = c >> 11, s = c & 2047;
          C[((size_t)(b * 16 + hh) * 128 + dd) * 2048 + s] = v;
        }
      }
}

// ---------------------------------------------------------------------------
// Fused RoPE + RMSNorm, in place on [B*H, S, D=128] bf16.
// ---------------------------------------------------------------------------
__global__ __launch_bounds__(256) void rope_rms(bf16_t* __restrict__ T,
                                                const float* __restrict__ Cs,
                                                const float* __restrict__ Sn) {
  const int wave = threadIdx.x >> 6, lane = threadIdx.x & 63;
#pragma unroll 1
  for (int rr = 0; rr < 8; ++rr) {
    const size_t row = (size_t)blockIdx.x * 32 + wave * 8 + rr;
    const int s = (int)(row & 2047);
    bf16_t* p = &T[row * 128 + 2 * lane];
    const float a0 = (float)p[0], a1 = (float)p[1];
    f32x2 cv = *(const f32x2*)&Cs[(size_t)s * 128 + 2 * lane];
    f32x2 sv = *(const f32x2*)&Sn[(size_t)s * 128 + 2 * lane];
    const float p0 = __shfl_xor(a0, 32);
    const float p1 = __shfl_xor(a1, 32);
    const float sg = (lane < 32) ? -1.f : 1.f;
    const float r0 = a0 * cv.x + sg * p0 * sv.x;
    const float r1 = a1 * cv.y + sg * p1 * sv.y;
    float ss = r0 * r0 + r1 * r1;
#pragma unroll
    for (int off = 1; off < 64; off <<= 1) ss += __shfl_xor(ss, off);
    const float inv = rsqrtf(ss * (1.0f / 128.0f) + 1e-6f);
    p[0] = (bf16_t)(r0 * inv);
    p[1] = (bf16_t)(r1 * inv);
  }
}

// ---------------------------------------------------------------------------
// Flash attention (round-3 structure) + permlane32_swap P-exchange, setprio,
// tree-max. Q,K [B*H][2048][128]; Vt [B*H][128][2048]; Y bf16 [B,S,H,D].
// ---------------------------------------------------------------------------
__global__ __launch_bounds__(512, 2) void attn_fwd(const bf16_t* __restrict__ Q,
                                                   const bf16_t* __restrict__ K,
                                                   const bf16_t* __restrict__ Vt,
                                                   bf16_t* __restrict__ Y) {
  __shared__ __attribute__((aligned(16))) bf16_t ldsK[2][64 * 128];
  __shared__ __attribute__((aligned(16))) bf16_t ldsV[2][128 * 64];
  const int tid = threadIdx.x, wave = tid >> 6, lane = tid & 63;
  const int l31 = lane & 31, hi = lane >> 5;
  const int pid = blockIdx.x;
  const int bh = (pid & 7) * 8 + ((pid >> 3) & 7);
  const int qb = pid >> 6;
  const int b = bh >> 4, h = bh & 15;
  const bf16_t* Qh = Q + (size_t)bh * 2048 * 128;
  const bf16_t* Kh = K + (size_t)bh * 2048 * 128;
  const bf16_t* Vh = Vt + (size_t)bh * 128 * 2048;
  const int q0 = qb * 256 + wave * 32;

  bf16x8 qf[8];
#pragma unroll
  for (int dk = 0; dk < 8; ++dk)
    qf[dk] = *(const bf16x8*)&Qh[(size_t)(q0 + l31) * 128 + dk * 16 + hi * 8];

  f32x16 ot[4] = {};
  float m_r = -1e30f, l_r = 0.f;
  const float scale = 0.08838834764831845f;

  auto stage = [&](int kt, int bu) {
#pragma unroll
    for (int i = 0; i < 2; ++i) {
      const int G = wave * 64 + lane + i * 512;
      char* dstK = (char*)&ldsK[bu][0] + (wave * 64 + i * 512) * 16;
      char* dstV = (char*)&ldsV[bu][0] + (wave * 64 + i * 512) * 16;
      const int kvr = G >> 4, glk = G & 15;
      gload16(Kh + (size_t)(kt * 64 + kvr) * 128 + ((glk ^ (kvr & 7)) * 8), dstK);
      const int dr = G >> 3, glv = G & 7;
      gload16(Vh + (size_t)dr * 2048 + kt * 64 + ((glv ^ (dr & 7)) * 8), dstV);
    }
  };

  stage(0, 0);
  __syncthreads();

  for (int kt = 0; kt < 32; ++kt) {
    const int bu = kt & 1;
    if (kt < 31) stage(kt + 1, bu ^ 1);

    // ---- S^T = K @ Q^T
    f32x16 sa0 = {}, sa1 = {};
    const int r7 = l31 & 7;
    __builtin_amdgcn_s_setprio(1);
#pragma unroll
    for (int dk = 0; dk < 8; ++dk) {
      const int g = ((dk << 1) | hi) ^ r7;
      bf16x8 kf0 = *(const bf16x8*)&ldsK[bu][l31 * 128 + g * 8];
      bf16x8 kf1 = *(const bf16x8*)&ldsK[bu][(32 + l31) * 128 + g * 8];
      sa0 = MFMA32(kf0, qf[dk], sa0);
      sa1 = MFMA32(kf1, qf[dk], sa1);
    }
    __builtin_amdgcn_s_setprio(0);

    // ---- online softmax, tree max
    float tm[16];
#pragma unroll
    for (int j = 0; j < 16; ++j) tm[j] = fmaxf(sa0[j], sa1[j]);
#pragma unroll
    for (int s = 8; s; s >>= 1)
#pragma unroll
      for (int j = 0; j < s; ++j) tm[j] = fmaxf(tm[j], tm[j + s]);
    float mx = fmaxf(tm[0], __shfl_xor(tm[0], 32)) * scale;
    if (__any(mx > m_r + 8.f)) {  // defer-max (T13)
      const float mn = fmaxf(m_r, mx);
      const float corr = __expf(m_r - mn);
      m_r = mn;
      l_r *= corr;
#pragma unroll
      for (int db = 0; db < 4; ++db)
#pragma unroll
        for (int j = 0; j < 16; ++j) ot[db][j] *= corr;
    }
    u32 w[2][8];
    float ssum = 0.f;
#pragma unroll
    for (int i = 0; i < 8; ++i) {
      const float p0 = __expf(sa0[2 * i] * scale - m_r);
      const float p1 = __expf(sa0[2 * i + 1] * scale - m_r);
      const float p2 = __expf(sa1[2 * i] * scale - m_r);
      const float p3 = __expf(sa1[2 * i + 1] * scale - m_r);
      ssum += (p0 + p1) + (p2 + p3);
      bf16x2 t0, t1;
      t0[0] = (bf16_t)p0; t0[1] = (bf16_t)p1;
      t1[0] = (bf16_t)p2; t1[1] = (bf16_t)p3;
      w[0][i] = __builtin_bit_cast(u32, t0);
      w[1][i] = __builtin_bit_cast(u32, t1);
    }
    ssum += __shfl_xor(ssum, 32);
    l_r += ssum;

    // ---- O^T += V^T @ P (P frags assembled via permlane32_swap)
#pragma unroll
    for (int ks = 0; ks < 4; ++ks) {
      const int tsel = ks >> 1, k4 = (ks & 1) * 4;
      u32 a0 = w[tsel][k4 + 0], b0 = w[tsel][k4 + 2];
      u32 a1 = w[tsel][k4 + 1], b1 = w[tsel][k4 + 3];
      pl32(a0, b0);
      pl32(a1, b1);
      u32x4 fw;
      fw.x = a0; fw.y = a1; fw.z = b0; fw.w = b1;
      const bf16x8 pf = __builtin_bit_cast(bf16x8, fw);
      const int gv = ((ks << 1) | hi) ^ r7;
      __builtin_amdgcn_s_setprio(1);
#pragma unroll
      for (int db = 0; db < 4; ++db) {
        bf16x8 vf = *(const bf16x8*)&ldsV[bu][(db * 32 + l31) * 64 + gv * 8];
        ot[db] = MFMA32(vf, pf, ot[db]);
      }
      __builtin_amdgcn_s_setprio(0);
    }
    __syncthreads();
  }

  const float rl = 1.f / l_r;
  const size_t yrow = ((size_t)(b * 2048 + q0 + l31) * 16 + h) * 128;
#pragma unroll
  for (int db = 0; db < 4; ++db)
#pragma unroll
    for (int g2 = 0; g2 < 4; ++g2) {
      bf16x4 ov;
#pragma unroll
      for (int j = 0; j < 4; ++j) ov[j] = (bf16_t)(ot[db][g2 * 4 + j] * rl);
      *(bf16x4*)&Y[yrow + db * 32 + g2 * 8 + hi * 4] = ov;
    }
}

// ---------------------------------------------------------------------------
extern "C" void kernel_launch(void* const* d_in, const int* in_sizes, int n_in,
                              void* d_out, int out_size, void* d_ws, size_t ws_size,
                              hipStream_t stream) {
  const float* x = (const float*)d_in[0];
  const float* cs = (const float*)d_in[1];
  const float* sn = (const float*)d_in[2];
  const float* Wq = (const float*)d_in[3];
  const float* Wk = (const float*)d_in[4];
  const float* Wv = (const float*)d_in[5];
  const float* Wo = (const float*)d_in[6];

  bf16_t* ws = (bf16_t*)d_ws;
  const size_t TSZ = (size_t)4 * 2048 * 2048;
  const size_t WSZ = (size_t)2048 * 2048;
  bf16_t* xb = ws;
  bf16_t* Wqb = ws + TSZ;
  bf16_t* Wkb = Wqb + WSZ;
  bf16_t* Wvb = Wkb + WSZ;
  bf16_t* Wob = Wvb + WSZ;
  bf16_t* Qb = ws + 2 * TSZ;
  bf16_t* Kb = Qb + TSZ;
  bf16_t* Vtb = Kb + TSZ;
  bf16_t* Yb = xb;

  cvt_bf16<<<16384, 256, 0, stream>>>(x, xb);
  cvt_w4<<<16384, 256, 0, stream>>>(Wq, Wk, Wv, Wo, Wqb, Wkb, Wvb, Wob);

  gemm8<0, bf16_t, 8><<<256, 512, 0, stream>>>(xb, Wqb, Qb);
  gemm8<0, bf16_t, 8><<<256, 512, 0, stream>>>(xb, Wkb, Kb);
  gemm8<2, bf16_t, 32><<<256, 512, 0, stream>>>(Wvb, xb, Vtb);
  rope_rms<<<4096, 256, 0, stream>>>(Qb, cs, sn);
  rope_rms<<<4096, 256, 0, stream>>>(Kb, cs, sn);
  attn_fwd<<<512, 512, 0, stream>>>(Qb, Kb, Vtb, Yb);
  gemm8<1, float, 8><<<256, 512, 0, stream>>>(Yb, Wob, (float*)d_out);
}

// Round 5
// 489.002 us; speedup vs baseline: 1.4045x; 1.0012x over previous
//
#include <hip/hip_runtime.h>
#include <hip/hip_bf16.h>
#include <math.h>

// B=4, S=2048, E=2048, H=16, D=128. Inputs/outputs FP32; internal bf16 MFMA, f32 acc.

typedef __bf16 bf16_t;
typedef __bf16 bf16x2 __attribute__((ext_vector_type(2)));
typedef __bf16 bf16x4 __attribute__((ext_vector_type(4)));
typedef __bf16 bf16x8 __attribute__((ext_vector_type(8)));
typedef float f32x2 __attribute__((ext_vector_type(2)));
typedef float f32x4 __attribute__((ext_vector_type(4)));
typedef float f32x16 __attribute__((ext_vector_type(16)));
typedef unsigned int u32;
typedef u32 u32x4 __attribute__((ext_vector_type(4)));

typedef __attribute__((address_space(1))) const void gas_cvoid;
typedef __attribute__((address_space(3))) void las_void;

#define MFMA16(a, b, c) __builtin_amdgcn_mfma_f32_16x16x32_bf16((a), (b), (c), 0, 0, 0)
#define MFMA32(a, b, c) __builtin_amdgcn_mfma_f32_32x32x16_bf16((a), (b), (c), 0, 0, 0)

__device__ __forceinline__ void gload16(const void* g, void* l) {
  __builtin_amdgcn_global_load_lds((gas_cvoid*)g, (las_void*)l, 16, 0, 0);
}
// lane[i] <-> lane[i+32] pairwise exchange of two regs (T12 primitive, m255):
// after: a = {a.lo, b.lo}, b = {a.hi, b.hi}
__device__ __forceinline__ void pl32(u32& a, u32& b) {
  asm volatile("v_permlane32_swap_b32 %0, %1" : "+v"(a), "+v"(b));
}

// ---------------------------------------------------------------------------
// f32 -> bf16 elementwise, 4 elems/thread.
// ---------------------------------------------------------------------------
__global__ __launch_bounds__(256) void cvt_bf16(const float* __restrict__ in,
                                                bf16_t* __restrict__ out) {
  const size_t i = ((size_t)blockIdx.x * 256 + threadIdx.x) * 4;
  f32x4 v = *(const f32x4*)&in[i];
  bf16x4 o;
#pragma unroll
  for (int j = 0; j < 4; ++j) o[j] = (bf16_t)v[j];
  *(bf16x4*)&out[i] = o;
}
// 4 weight matrices (4.19M elems each) in one launch: 4096 blocks per tensor.
__global__ __launch_bounds__(256) void cvt_w4(const float* __restrict__ w0,
                                              const float* __restrict__ w1,
                                              const float* __restrict__ w2,
                                              const float* __restrict__ w3,
                                              bf16_t* __restrict__ o0,
                                              bf16_t* __restrict__ o1,
                                              bf16_t* __restrict__ o2,
                                              bf16_t* __restrict__ o3) {
  const int which = blockIdx.x >> 12;
  const float* in = which == 0 ? w0 : which == 1 ? w1 : which == 2 ? w2 : w3;
  bf16_t* out = which == 0 ? o0 : which == 1 ? o1 : which == 2 ? o2 : o3;
  const size_t i = ((size_t)(blockIdx.x & 4095) * 256 + threadIdx.x) * 4;
  f32x4 v = *(const f32x4*)&in[i];
  bf16x4 o;
#pragma unroll
  for (int j = 0; j < 4; ++j) o[j] = (bf16_t)v[j];
  *(bf16x4*)&out[i] = o;
}

// ---------------------------------------------------------------------------
// 8-phase NT GEMM: C[M][N] = A[M][2048] @ Bt[N][2048]^T, 256x256 tile, BK=64.
// (unchanged from round 4 -- ~1200 TF effective)
// ---------------------------------------------------------------------------
template <int MODE, typename CT, int NT_T>
__global__ __launch_bounds__(512, 2) void gemm8(const bf16_t* __restrict__ A,
                                                const bf16_t* __restrict__ Bt,
                                                CT* __restrict__ C) {
  constexpr int K = 2048;
  __shared__ __attribute__((aligned(16))) char lds[131072];
  const int tid = threadIdx.x;
  const int wave = tid >> 6, lane = tid & 63;
  const int bid = blockIdx.x;
  const int swz = (bid & 7) * 32 + (bid >> 3);  // grid 256, bijective XCD swizzle
  const int m0 = (swz / NT_T) * 256, n0 = (swz % NT_T) * 256;

  const int srow = tid >> 3;
  const int scol = ((tid & 7) ^ (srow & 7)) * 8;
  const bf16_t* aBase = A + (size_t)(m0 + srow) * K + scol;
  const bf16_t* bBase = Bt + (size_t)(n0 + srow) * K + scol;

  const int wm = wave >> 2, wn = wave & 3;
  const int l15 = lane & 15, l4 = lane >> 4;
  const int axor = l15 & 7;

  f32x4 acc[8][4] = {};

  auto stageA = [&](int tt, int nbuf) {
#pragma unroll
    for (int h = 0; h < 2; ++h)
#pragma unroll
      for (int cc = 0; cc < 2; ++cc)
        gload16(aBase + (size_t)(h * 128 + cc * 64) * K + tt * 64,
                lds + nbuf * 65536 + h * 16384 + cc * 8192 + wave * 1024);
  };
  auto stageB = [&](int tt, int nbuf) {
#pragma unroll
    for (int h = 0; h < 2; ++h)
#pragma unroll
      for (int cc = 0; cc < 2; ++cc)
        gload16(bBase + (size_t)(h * 128 + cc * 64) * K + tt * 64,
                lds + nbuf * 65536 + 32768 + h * 16384 + cc * 8192 + wave * 1024);
  };

  stageA(0, 0);
  stageB(0, 0);
  __syncthreads();

  for (int t = 0; t < 32; ++t) {
    const int buf = t & 1, nbuf = buf ^ 1;
    const char* la = lds + buf * 65536 + wm * 16384;
    const char* lb = lds + buf * 65536 + 32768 + (wn >> 1) * 16384 + (wn & 1) * 8192;
    bf16x8 bF[4][2];
#pragma unroll
    for (int q = 0; q < 4; ++q) {
      bf16x8 aF[2][2];
#pragma unroll
      for (int dm = 0; dm < 2; ++dm)
#pragma unroll
        for (int kk = 0; kk < 2; ++kk)
          aF[dm][kk] = *(const bf16x8*)(la + ((q * 2 + dm) * 16 + l15) * 128 +
                                        ((kk * 4 + l4) ^ axor) * 16);
      if (q == 0) {
#pragma unroll
        for (int ni = 0; ni < 4; ++ni)
#pragma unroll
          for (int kk = 0; kk < 2; ++kk)
            bF[ni][kk] = *(const bf16x8*)(lb + (ni * 16 + l15) * 128 +
                                          ((kk * 4 + l4) ^ axor) * 16);
        if (t < 31) stageA(t + 1, nbuf);
      }
      if (q == 1 && t < 31) stageB(t + 1, nbuf);
      __builtin_amdgcn_s_barrier();
      __builtin_amdgcn_s_setprio(1);
#pragma unroll
      for (int kk = 0; kk < 2; ++kk)
#pragma unroll
        for (int dm = 0; dm < 2; ++dm)
#pragma unroll
          for (int ni = 0; ni < 4; ++ni)
            acc[q * 2 + dm][ni] = MFMA16(aF[dm][kk], bF[ni][kk], acc[q * 2 + dm][ni]);
      __builtin_amdgcn_s_setprio(0);
      if (q < 3)
        __builtin_amdgcn_s_barrier();
      else
        __syncthreads();  // drains vmcnt(0): tile t+1 landed; buf t free
    }
  }

  const int rBase = m0 + wm * 128 + l4 * 4;
  const int cBase = n0 + wn * 64 + l15;
#pragma unroll
  for (int mi = 0; mi < 8; ++mi)
#pragma unroll
    for (int ni = 0; ni < 4; ++ni)
#pragma unroll
      for (int j = 0; j < 4; ++j) {
        const int r = rBase + mi * 16 + j;
        const int c = cBase + ni * 16;
        const CT v = (CT)acc[mi][ni][j];
        if (MODE == 0) {
          const int b = r >> 11, s = r & 2047, hh = c >> 7, d = c & 127;
          C[(((size_t)(b * 16 + hh)) * 2048 + s) * 128 + d] = v;
        } else if (MODE == 1) {
          C[(size_t)r * 2048 + c] = v;
        } else {  // r = h*128+dd (Wv row), c = b*2048+s
          const int hh = r >> 7, dd = r & 127, b = c >> 11, s = c & 2047;
          C[((size_t)(b * 16 + hh) * 128 + dd) * 2048 + s] = v;
        }
      }
}

// ---------------------------------------------------------------------------
// Fused RoPE + RMSNorm, in place on [B*H, S, D=128] bf16.
// ---------------------------------------------------------------------------
__global__ __launch_bounds__(256) void rope_rms(bf16_t* __restrict__ T,
                                                const float* __restrict__ Cs,
                                                const float* __restrict__ Sn) {
  const int wave = threadIdx.x >> 6, lane = threadIdx.x & 63;
#pragma unroll 1
  for (int rr = 0; rr < 8; ++rr) {
    const size_t row = (size_t)blockIdx.x * 32 + wave * 8 + rr;
    const int s = (int)(row & 2047);
    bf16_t* p = &T[row * 128 + 2 * lane];
    const float a0 = (float)p[0], a1 = (float)p[1];
    f32x2 cv = *(const f32x2*)&Cs[(size_t)s * 128 + 2 * lane];
    f32x2 sv = *(const f32x2*)&Sn[(size_t)s * 128 + 2 * lane];
    const float p0 = __shfl_xor(a0, 32);
    const float p1 = __shfl_xor(a1, 32);
    const float sg = (lane < 32) ? -1.f : 1.f;
    const float r0 = a0 * cv.x + sg * p0 * sv.x;
    const float r1 = a1 * cv.y + sg * p1 * sv.y;
    float ss = r0 * r0 + r1 * r1;
#pragma unroll
    for (int off = 1; off < 64; off <<= 1) ss += __shfl_xor(ss, off);
    const float inv = rsqrtf(ss * (1.0f / 128.0f) + 1e-6f);
    p[0] = (bf16_t)(r0 * inv);
    p[1] = (bf16_t)(r1 * inv);
  }
}

// ---------------------------------------------------------------------------
// Flash attention, counted-vmcnt pipeline (T4). Structure per kt:
//   {QK (reads ldsK[bu]); softmax; PV (reads ldsV[bu])}
//   s_barrier                    -- all waves done reading buf bu (no drain)
//   stage(kt+2 -> buf bu)        -- refill freed buffer; queue never drains
//   s_waitcnt vmcnt(4)           -- only tile kt+1's 4 loads; kt+2's stay in flight
//   s_barrier + sched_barrier(0) -- tile kt+1 resident for all waves (rule #18)
// ---------------------------------------------------------------------------
__global__ __launch_bounds__(512, 2) void attn_fwd(const bf16_t* __restrict__ Q,
                                                   const bf16_t* __restrict__ K,
                                                   const bf16_t* __restrict__ Vt,
                                                   bf16_t* __restrict__ Y) {
  __shared__ __attribute__((aligned(16))) bf16_t ldsK[2][64 * 128];
  __shared__ __attribute__((aligned(16))) bf16_t ldsV[2][128 * 64];
  const int tid = threadIdx.x, wave = tid >> 6, lane = tid & 63;
  const int l31 = lane & 31, hi = lane >> 5;
  const int pid = blockIdx.x;
  const int bh = (pid & 7) * 8 + ((pid >> 3) & 7);
  const int qb = pid >> 6;
  const int b = bh >> 4, h = bh & 15;
  const bf16_t* Qh = Q + (size_t)bh * 2048 * 128;
  const bf16_t* Kh = K + (size_t)bh * 2048 * 128;
  const bf16_t* Vh = Vt + (size_t)bh * 128 * 2048;
  const int q0 = qb * 256 + wave * 32;

  bf16x8 qf[8];
#pragma unroll
  for (int dk = 0; dk < 8; ++dk)
    qf[dk] = *(const bf16x8*)&Qh[(size_t)(q0 + l31) * 128 + dk * 16 + hi * 8];

  f32x16 ot[4] = {};
  float m_r = -1e30f, l_r = 0.f;
  const float scale = 0.08838834764831845f;

  auto stage = [&](int kt, int bu) {
#pragma unroll
    for (int i = 0; i < 2; ++i) {
      const int G = wave * 64 + lane + i * 512;
      char* dstK = (char*)&ldsK[bu][0] + (wave * 64 + i * 512) * 16;
      char* dstV = (char*)&ldsV[bu][0] + (wave * 64 + i * 512) * 16;
      const int kvr = G >> 4, glk = G & 15;
      gload16(Kh + (size_t)(kt * 64 + kvr) * 128 + ((glk ^ (kvr & 7)) * 8), dstK);
      const int dr = G >> 3, glv = G & 7;
      gload16(Vh + (size_t)dr * 2048 + kt * 64 + ((glv ^ (dr & 7)) * 8), dstV);
    }
  };

  // prologue: issue tiles 0 and 1 (8 loads/wave); wait tile 0 only (4 stay in flight)
  stage(0, 0);
  stage(1, 1);
  asm volatile("s_waitcnt vmcnt(4)" ::: "memory");
  __builtin_amdgcn_s_barrier();
  __builtin_amdgcn_sched_barrier(0);

  for (int kt = 0; kt < 32; ++kt) {
    const int bu = kt & 1;

    // ---- S^T = K @ Q^T
    f32x16 sa0 = {}, sa1 = {};
    const int r7 = l31 & 7;
    __builtin_amdgcn_s_setprio(1);
#pragma unroll
    for (int dk = 0; dk < 8; ++dk) {
      const int g = ((dk << 1) | hi) ^ r7;
      bf16x8 kf0 = *(const bf16x8*)&ldsK[bu][l31 * 128 + g * 8];
      bf16x8 kf1 = *(const bf16x8*)&ldsK[bu][(32 + l31) * 128 + g * 8];
      sa0 = MFMA32(kf0, qf[dk], sa0);
      sa1 = MFMA32(kf1, qf[dk], sa1);
    }
    __builtin_amdgcn_s_setprio(0);

    // ---- online softmax, tree max
    float tm[16];
#pragma unroll
    for (int j = 0; j < 16; ++j) tm[j] = fmaxf(sa0[j], sa1[j]);
#pragma unroll
    for (int s = 8; s; s >>= 1)
#pragma unroll
      for (int j = 0; j < s; ++j) tm[j] = fmaxf(tm[j], tm[j + s]);
    float mx = fmaxf(tm[0], __shfl_xor(tm[0], 32)) * scale;
    if (__any(mx > m_r + 8.f)) {  // defer-max (T13)
      const float mn = fmaxf(m_r, mx);
      const float corr = __expf(m_r - mn);
      m_r = mn;
      l_r *= corr;
#pragma unroll
      for (int db = 0; db < 4; ++db)
#pragma unroll
        for (int j = 0; j < 16; ++j) ot[db][j] *= corr;
    }
    u32 w[2][8];
    float ssum = 0.f;
#pragma unroll
    for (int i = 0; i < 8; ++i) {
      const float p0 = __expf(sa0[2 * i] * scale - m_r);
      const float p1 = __expf(sa0[2 * i + 1] * scale - m_r);
      const float p2 = __expf(sa1[2 * i] * scale - m_r);
      const float p3 = __expf(sa1[2 * i + 1] * scale - m_r);
      ssum += (p0 + p1) + (p2 + p3);
      bf16x2 t0, t1;
      t0[0] = (bf16_t)p0; t0[1] = (bf16_t)p1;
      t1[0] = (bf16_t)p2; t1[1] = (bf16_t)p3;
      w[0][i] = __builtin_bit_cast(u32, t0);
      w[1][i] = __builtin_bit_cast(u32, t1);
    }
    ssum += __shfl_xor(ssum, 32);
    l_r += ssum;

    // ---- O^T += V^T @ P (P frags assembled via permlane32_swap)
#pragma unroll
    for (int ks = 0; ks < 4; ++ks) {
      const int tsel = ks >> 1, k4 = (ks & 1) * 4;
      u32 a0 = w[tsel][k4 + 0], b0 = w[tsel][k4 + 2];
      u32 a1 = w[tsel][k4 + 1], b1 = w[tsel][k4 + 3];
      pl32(a0, b0);
      pl32(a1, b1);
      u32x4 fw;
      fw.x = a0; fw.y = a1; fw.z = b0; fw.w = b1;
      const bf16x8 pf = __builtin_bit_cast(bf16x8, fw);
      const int gv = ((ks << 1) | hi) ^ r7;
      __builtin_amdgcn_s_setprio(1);
#pragma unroll
      for (int db = 0; db < 4; ++db) {
        bf16x8 vf = *(const bf16x8*)&ldsV[bu][(db * 32 + l31) * 64 + gv * 8];
        ot[db] = MFMA32(vf, pf, ot[db]);
      }
      __builtin_amdgcn_s_setprio(0);
    }

    // ---- counted-vmcnt buffer rotation (T4: never drain to 0 mid-loop)
    __builtin_amdgcn_s_barrier();        // all waves done reading buf bu
    __builtin_amdgcn_sched_barrier(0);
    if (kt < 30) {
      stage(kt + 2, bu);                 // refill just-freed buffer
      asm volatile("s_waitcnt vmcnt(4)" ::: "memory");  // tile kt+1 landed
    } else {
      asm volatile("s_waitcnt vmcnt(0)" ::: "memory");
    }
    __builtin_amdgcn_s_barrier();        // tile kt+1 visible to all waves
    __builtin_amdgcn_sched_barrier(0);
  }

  const float rl = 1.f / l_r;
  const size_t yrow = ((size_t)(b * 2048 + q0 + l31) * 16 + h) * 128;
#pragma unroll
  for (int db = 0; db < 4; ++db)
#pragma unroll
    for (int g2 = 0; g2 < 4; ++g2) {
      bf16x4 ov;
#pragma unroll
      for (int j = 0; j < 4; ++j) ov[j] = (bf16_t)(ot[db][g2 * 4 + j] * rl);
      *(bf16x4*)&Y[yrow + db * 32 + g2 * 8 + hi * 4] = ov;
    }
}

// ---------------------------------------------------------------------------
extern "C" void kernel_launch(void* const* d_in, const int* in_sizes, int n_in,
                              void* d_out, int out_size, void* d_ws, size_t ws_size,
                              hipStream_t stream) {
  const float* x = (const float*)d_in[0];
  const float* cs = (const float*)d_in[1];
  const float* sn = (const float*)d_in[2];
  const float* Wq = (const float*)d_in[3];
  const float* Wk = (const float*)d_in[4];
  const float* Wv = (const float*)d_in[5];
  const float* Wo = (const float*)d_in[6];

  bf16_t* ws = (bf16_t*)d_ws;
  const size_t TSZ = (size_t)4 * 2048 * 2048;
  const size_t WSZ = (size_t)2048 * 2048;
  bf16_t* xb = ws;
  bf16_t* Wqb = ws + TSZ;
  bf16_t* Wkb = Wqb + WSZ;
  bf16_t* Wvb = Wkb + WSZ;
  bf16_t* Wob = Wvb + WSZ;
  bf16_t* Qb = ws + 2 * TSZ;
  bf16_t* Kb = Qb + TSZ;
  bf16_t* Vtb = Kb + TSZ;
  bf16_t* Yb = xb;

  cvt_bf16<<<16384, 256, 0, stream>>>(x, xb);
  cvt_w4<<<16384, 256, 0, stream>>>(Wq, Wk, Wv, Wo, Wqb, Wkb, Wvb, Wob);

  gemm8<0, bf16_t, 8><<<256, 512, 0, stream>>>(xb, Wqb, Qb);
  gemm8<0, bf16_t, 8><<<256, 512, 0, stream>>>(xb, Wkb, Kb);
  gemm8<2, bf16_t, 32><<<256, 512, 0, stream>>>(Wvb, xb, Vtb);
  rope_rms<<<4096, 256, 0, stream>>>(Qb, cs, sn);
  rope_rms<<<4096, 256, 0, stream>>>(Kb, cs, sn);
  attn_fwd<<<512, 512, 0, stream>>>(Qb, Kb, Vtb, Yb);
  gemm8<1, float, 8><<<256, 512, 0, stream>>>(Yb, Wob, (float*)d_out);
}